// Round 1
// 700.296 us; speedup vs baseline: 1.0568x; 1.0568x over previous
//
#include <hip/hip_runtime.h>
#include <cmath>

// ConvLSTM2D forward, bf16 MFMA implicit GEMM, R6: async global_load_lds B-slab
// pipeline (triple-buffered, 2-deep prefetch, counted vmcnt + raw barriers).
// B=8, T=16, H=W=96, Cin=8, F=64 (4F=256 gates), 3x3 SAME, 16 sequential steps.
// Per step GEMM: M=73728, N=256, K=672 (21 K-steps of 32: 18 h-taps + 3 packed x).
// Block tile: M=128 (16x8 spatial) x N=64 (fch 16-slice x 4 gates); wave = M=32.
// R6 vs R5: B slabs stream global->LDS via global_load_lds (no VGPR round trip,
// no per-iter ds_write), issued 2 iterations ahead into a 3-slab ring; per-iter
// sync is s_waitcnt vmcnt(1) + s_barrier (never a full drain in steady state).
// xpatch folded into hpatch's 8-ushort pad so LDS stays 38.2KB -> 4 blocks/CU.

#define HTOT 96
#define WTOT 96
#define CINX 8
#define FF   64
#define G4   256
#define BB   8
#define TT   16
#define HP   72                    // padded ushorts per halo position (64 h + 8 x)
#define NPOS (BB*HTOT*WTOT)        // 73728 global positions

typedef __attribute__((ext_vector_type(8))) short short8;   // 8 bf16 = 4 VGPRs
typedef __attribute__((ext_vector_type(4))) float floatx4;

union U16 { uint4 u; short8 s; };

__device__ __forceinline__ float hsig(float z) {
    return fminf(fmaxf(0.2f * z + 0.5f, 0.f), 1.f);
}

__device__ __forceinline__ float ftanh(float x) {
    float e = __expf(-2.f * fabsf(x));
    float t = (1.f - e) / (1.f + e);
    return copysignf(t, x);
}

__device__ __forceinline__ ushort f2bf(float f) {            // RNE fp32->bf16
    unsigned u = __float_as_uint(f);
    u = (u + 0x7fff + ((u >> 16) & 1)) >> 16;
    return (ushort)u;
}

// async 16B global->LDS (dest must be wave-uniform base + lane*16 -- it is:
// dest = bslab + slab*4096 + tid*16, tid = w*64+lane)
__device__ __forceinline__ void async16(const uint4* g, uint4* l) {
    __builtin_amdgcn_global_load_lds(
        (const __attribute__((address_space(1))) void*)g,
        (__attribute__((address_space(3))) void*)l, 16, 0, 0);
}

// ---- prep: x fp32 -> bf16 (all T at once), layout [b,t,y,x,8] ----
__global__ __launch_bounds__(256) void conv_x_bf16(const float* __restrict__ x,
                                                   ushort* __restrict__ xbf, int n4) {
    int i = blockIdx.x * 256 + threadIdx.x;
    if (i >= n4) return;
    float4 v = ((const float4*)x)[i];
    ushort4 o;
    o.x = f2bf(v.x); o.y = f2bf(v.y); o.z = f2bf(v.z); o.w = f2bf(v.w);
    ((ushort4*)xbf)[i] = o;
}

// ---- prep: weights -> per-slice slab stream Bp[(slice*21+s)*256 + g*64 + lane] (16B units)
__global__ __launch_bounds__(256) void prep_w(const float* __restrict__ Wx,
                                              const float* __restrict__ Wh,
                                              ushort* __restrict__ Bp) {
    int idx = blockIdx.x * 256 + threadIdx.x;
    if (idx >= 4 * 21 * 256) return;                 // 21504
    int lane = idx & 63;
    int g = (idx >> 6) & 3;
    int rest = idx >> 8;                             // slice*21 + s
    int s = rest % 21, slice = rest / 21;
    int q = lane >> 4, col = lane & 15;
    int n = g * 64 + slice * 16 + col;
    ushort o[8];
    if (s < 18) {
        int tap = s >> 1;
        int cbase = (s & 1) * 32 + q * 8;
        #pragma unroll
        for (int j = 0; j < 8; ++j)
            o[j] = f2bf(Wh[((size_t)tap * FF + cbase + j) * G4 + n]);
    } else {
        int tap = (s - 18) * 4 + q;                  // packed x-taps; >8 -> zero pad
        #pragma unroll
        for (int j = 0; j < 8; ++j)
            o[j] = (tap < 9) ? f2bf(Wx[((size_t)tap * CINX + j) * G4 + n]) : (ushort)0;
    }
    U16 u;
    #pragma unroll
    for (int j = 0; j < 8; ++j) ((ushort*)&u)[j] = o[j];
    ((uint4*)Bp)[idx] = u.u;
}

// ---- main step kernel ----
__global__ __launch_bounds__(256, 4) void convlstm_mfma(
    const ushort* __restrict__ xbf, int t,
    const ushort* __restrict__ hS_in,     // [slice][pos][16] bf16
    ushort* __restrict__ hS_out,
    float* __restrict__ cS,               // [slice][pos][16] fp32
    const ushort* __restrict__ Bp,
    const float* __restrict__ bias,
    float* __restrict__ out, int last)
{
    __shared__ __align__(16) ushort hpatch[180 * HP];  // 18x10 halo: 64 h-ch + 8 x-ch pad
    __shared__ uint4 bslab[3 * 256];                   // 3-slab ring, 4KB each

    const int tid = threadIdx.x;
    const int x0 = blockIdx.x * 8, y0 = blockIdx.y * 16;
    const int bb = blockIdx.z >> 2, slice = blockIdx.z & 3;

    const uint4* Bp4 = (const uint4*)Bp;
    const uint4* src = Bp4 + (size_t)(slice * 21) * 256;

    // issue slab 0,1 loads first (drained by the prologue __syncthreads)
    async16(src + tid,       &bslab[tid]);
    async16(src + 256 + tid, &bslab[256 + tid]);

    // stage h halo patch from slice-major layout (8-ch granules)
    for (int e = tid; e < 1440; e += 256) {
        int part = e / 180, pp = e - part * 180;     // part = s8*2+half
        int py = pp / 10, px = pp - py * 10;
        int gy = y0 - 1 + py, gx = x0 - 1 + px;
        uint4 v = make_uint4(0, 0, 0, 0);
        if (gy >= 0 && gy < HTOT && gx >= 0 && gx < WTOT) {
            int s8 = part >> 1, half = part & 1;
            size_t gpos = ((size_t)bb * HTOT + gy) * WTOT + gx;
            v = *(const uint4*)(hS_in + ((size_t)s8 * NPOS + gpos) * 16 + half * 8);
        }
        *(uint4*)(hpatch + pp * HP + part * 8) = v;
    }
    // stage x patch into the 8-ushort pad at offset 64 of each position
    if (tid < 180) {
        int py = tid / 10, px = tid - py * 10;
        int gy = y0 - 1 + py, gx = x0 - 1 + px;
        uint4 v = make_uint4(0, 0, 0, 0);
        if (gy >= 0 && gy < HTOT && gx >= 0 && gx < WTOT)
            v = *(const uint4*)(xbf + ((((size_t)bb * TT + t) * HTOT + gy) * WTOT + gx) * CINX);
        *(uint4*)(hpatch + tid * HP + 64) = v;
    }

    const int w = tid >> 6, lane = tid & 63, q = lane >> 4, col = lane & 15;

    int pos0[2];
    #pragma unroll
    for (int mt = 0; mt < 2; ++mt)
        pos0[mt] = (w * 4 + mt * 2 + (col >> 3)) * 10 + (col & 7);

    floatx4 acc[2][4];
    #pragma unroll
    for (int g = 0; g < 4; ++g) {
        float bv = bias[g * 64 + slice * 16 + col];
        acc[0][g] = (floatx4){bv, bv, bv, bv};
        acc[1][g] = (floatx4){bv, bv, bv, bv};
    }

    __syncthreads();   // full drain once: hpatch writes + slab 0,1 complete

    // ---- K-loop: 21 steps of K=32; B slab ring via global_load_lds, 2 ahead ----
    #pragma unroll
    for (int s = 0; s < 21; ++s) {
        if (s + 2 < 21)
            async16(src + (s + 2) * 256 + tid, &bslab[((s + 2) % 3) * 256 + tid]);
        const uint4* slab = &bslab[(s % 3) * 256];
        U16 b4[4], a4[2];
        #pragma unroll
        for (int g = 0; g < 4; ++g)
            b4[g].u = slab[g * 64 + lane];
        if (s < 18) {
            int tap = s >> 1, kh = s & 1;
            int dy = tap / 3, dx = tap - 3 * dy;
            #pragma unroll
            for (int mt = 0; mt < 2; ++mt)
                a4[mt].u = *(const uint4*)(hpatch + (pos0[mt] + dy * 10 + dx) * HP + kh * 32 + q * 8);
        } else {
            int tap = (s - 18) * 4 + q; if (tap > 8) tap = 8;   // padded taps: B rows are 0
            int dy = tap / 3, dx = tap - 3 * dy;
            #pragma unroll
            for (int mt = 0; mt < 2; ++mt)
                a4[mt].u = *(const uint4*)(hpatch + (pos0[mt] + dy * 10 + dx) * HP + 64);
        }
        #pragma unroll
        for (int mt = 0; mt < 2; ++mt)
            #pragma unroll
            for (int g = 0; g < 4; ++g)
                acc[mt][g] = __builtin_amdgcn_mfma_f32_16x16x32_bf16(a4[mt].s, b4[g].s, acc[mt][g], 0, 0, 0);
        if (s < 20) {
            // need slab s+1 resident before anyone reads it next iter.
            // outstanding per thread after this wait: the slab s+2 load only.
            if (s < 19) asm volatile("s_waitcnt vmcnt(1)" ::: "memory");
            else        asm volatile("s_waitcnt vmcnt(0)" ::: "memory");
            __builtin_amdgcn_s_barrier();
            __builtin_amdgcn_sched_barrier(0);
        }
    }

    // ---- epilogue: gates fused in-register; contiguous slice-major writes ----
    #pragma unroll
    for (int mt = 0; mt < 2; ++mt) {
        #pragma unroll
        for (int r = 0; r < 4; ++r) {
            int m = w * 32 + mt * 16 + q * 4 + r;     // 0..127
            int gy = y0 + (m >> 3), gx = x0 + (m & 7);
            size_t gpos = ((size_t)bb * HTOT + gy) * WTOT + gx;
            size_t idx = ((size_t)slice * NPOS + gpos) * 16 + col;
            float zi = acc[mt][0][r], zf = acc[mt][1][r];
            float zg = acc[mt][2][r], zo = acc[mt][3][r];
            float cn = hsig(zf) * cS[idx] + hsig(zi) * ftanh(zg);
            cS[idx] = cn;
            float hn = hsig(zo) * ftanh(cn);
            hS_out[idx] = f2bf(hn);
            if (last) out[gpos * 64 + slice * 16 + col] = hn;
        }
    }
}

extern "C" void kernel_launch(void* const* d_in, const int* in_sizes, int n_in,
                              void* d_out, int out_size, void* d_ws, size_t ws_size,
                              hipStream_t stream) {
    const float* x  = (const float*)d_in[0];
    const float* Wx = (const float*)d_in[1];
    const float* Wh = (const float*)d_in[2];
    const float* b  = (const float*)d_in[3];

    const size_t NX = (size_t)BB * TT * HTOT * WTOT * CINX;  // 9,437,184
    const size_t NH = (size_t)NPOS * FF;                     // 4,718,592

    char* ws = (char*)d_ws;
    ushort* xbf = (ushort*)ws;                  ws += NX * 2;            // 18.9 MB
    ushort* hS0 = (ushort*)ws;                  ws += NH * 2;            //  9.4 MB
    ushort* hS1 = (ushort*)ws;                  ws += NH * 2;            //  9.4 MB
    float*  cS  = (float*)ws;                   ws += NH * 4;            // 18.9 MB
    ushort* Bp  = (ushort*)ws;                                           // 336 KB

    hipMemsetAsync(hS0, 0, NH * 2, stream);
    hipMemsetAsync(cS,  0, NH * 4, stream);

    conv_x_bf16<<<(int)((NX / 4 + 255) / 256), 256, 0, stream>>>(x, xbf, (int)(NX / 4));
    prep_w<<<(4 * 21 * 256 + 255) / 256, 256, 0, stream>>>(Wx, Wh, Bp);

    dim3 grid(WTOT / 8, HTOT / 16, BB * 4);
    for (int t = 0; t < TT; ++t) {
        const ushort* hin = (t & 1) ? hS1 : hS0;
        ushort* hout      = (t & 1) ? hS0 : hS1;
        convlstm_mfma<<<grid, 256, 0, stream>>>(xbf, t, hin, hout, cS, Bp, b,
                                                (float*)d_out, t == TT - 1);
    }
}

// Round 2
// 587.672 us; speedup vs baseline: 1.2593x; 1.1916x over previous
//
#include <hip/hip_runtime.h>
#include <cmath>

// ConvLSTM2D forward, bf16 MFMA implicit GEMM, R7: LDS-traffic-minimized.
// B=8, T=16, H=W=96, Cin=8, F=64 (4F=256 gates), 3x3 SAME, 16 sequential steps.
// Per step GEMM: M=73728, N=256, K=672 (21 K-steps of 32: 18 h + 3 packed x).
// R7 vs R6 (R6 was LDS-read-throughput-bound: 6 ds_read_b128/wave/step for 8 MFMA):
//  - block M=192 (12x16 spatial), wave M=48 (3 MFMA tiles): 4 B + ~1.9 A reads
//    per 12 MFMAs (0.49 reads/MFMA vs 0.75).
//  - slab order (dx,kh,dy) + 4-slot A-register window: h A-reads 54->30/wave.
//  - halo staged via global_load_lds into [plane=kh*4+q][256pos][8ch] (per-lane
//    gather source, lane-linear dest; OOB lanes read zpad) - no staging ds_writes.
//  - grid 6x8x32=1536, LDS 48KB, VGPR<=128 -> 3 blocks/CU, exactly 2 rounds.
// B slab ring-3 via global_load_lds, 2-deep, counted vmcnt (R6 scheme kept).

#define HTOT 96
#define WTOT 96
#define CINX 8
#define FF   64
#define G4   256
#define BB   8
#define TT   16
#define NPOS (BB*HTOT*WTOT)        // 73728 global positions

typedef __attribute__((ext_vector_type(8))) short short8;   // 8 bf16 = 4 VGPRs
typedef __attribute__((ext_vector_type(4))) float floatx4;

union U16 { uint4 u; short8 s; };

__device__ __forceinline__ float hsig(float z) {
    return fminf(fmaxf(0.2f * z + 0.5f, 0.f), 1.f);
}

__device__ __forceinline__ float ftanh(float x) {
    float e = __expf(-2.f * fabsf(x));
    float t = (1.f - e) / (1.f + e);
    return copysignf(t, x);
}

__device__ __forceinline__ ushort f2bf(float f) {            // RNE fp32->bf16
    unsigned u = __float_as_uint(f);
    u = (u + 0x7fff + ((u >> 16) & 1)) >> 16;
    return (ushort)u;
}

// async 16B global->LDS; global source is per-lane, LDS dest = uniform base + lane*16
__device__ __forceinline__ void async16(const void* g, void* l) {
    __builtin_amdgcn_global_load_lds(
        (const __attribute__((address_space(1))) void*)g,
        (__attribute__((address_space(3))) void*)l, 16, 0, 0);
}

// ---- prep: x fp32 -> bf16 (all T at once), layout [b,t,y,x,8] ----
__global__ __launch_bounds__(256) void conv_x_bf16(const float* __restrict__ x,
                                                   ushort* __restrict__ xbf, int n4) {
    int i = blockIdx.x * 256 + threadIdx.x;
    if (i >= n4) return;
    float4 v = ((const float4*)x)[i];
    ushort4 o;
    o.x = f2bf(v.x); o.y = f2bf(v.y); o.z = f2bf(v.z); o.w = f2bf(v.w);
    ((ushort4*)xbf)[i] = o;
}

// ---- prep: weights -> per-slice slab stream, slab s order = dx*6 + kh*3 + dy ----
// Bp[(slice*21+s)*256 + g*64 + lane] (16B units); lane(q,col) holds B rows q*8..q*8+7
__global__ __launch_bounds__(256) void prep_w(const float* __restrict__ Wx,
                                              const float* __restrict__ Wh,
                                              ushort* __restrict__ Bp) {
    int idx = blockIdx.x * 256 + threadIdx.x;
    if (idx >= 4 * 21 * 256) return;                 // 21504
    int lane = idx & 63;
    int g = (idx >> 6) & 3;
    int rest = idx >> 8;                             // slice*21 + s
    int s = rest % 21, slice = rest / 21;
    int q = lane >> 4, col = lane & 15;
    int n = g * 64 + slice * 16 + col;
    ushort o[8];
    if (s < 18) {
        int dxw = s / 6, rem = s - 6 * dxw;
        int khw = rem / 3, dyw = rem - 3 * khw;
        int tap = dyw * 3 + dxw;
        int cbase = khw * 32 + q * 8;
        #pragma unroll
        for (int j = 0; j < 8; ++j)
            o[j] = f2bf(Wh[((size_t)tap * FF + cbase + j) * G4 + n]);
    } else {
        int tap = (s - 18) * 4 + q;                  // packed x-taps; >8 -> zero pad
        #pragma unroll
        for (int j = 0; j < 8; ++j)
            o[j] = (tap < 9) ? f2bf(Wx[((size_t)tap * CINX + j) * G4 + n]) : (ushort)0;
    }
    U16 u;
    #pragma unroll
    for (int j = 0; j < 8; ++j) ((ushort*)&u)[j] = o[j];
    ((uint4*)Bp)[idx] = u.u;
}

// ---- main step kernel ----
__global__ __launch_bounds__(256, 4) void convlstm_mfma(
    const ushort* __restrict__ xbf, int t,
    const ushort* __restrict__ hS_in,     // [slice][pos][16] bf16
    ushort* __restrict__ hS_out,
    float* __restrict__ cS,               // [slice][pos][16] fp32
    const ushort* __restrict__ Bp,
    const float* __restrict__ bias,
    const uint4* __restrict__ zpad,       // 64B of zeros for OOB halo lanes
    float* __restrict__ out, int last)
{
    // channel-plane halo: plane p = kh*4+q holds channels p*8..p*8+7 for 256 pos
    __shared__ __align__(16) ushort hplanes[8 * 2048];   // 8 x 4KB = 32KB
    __shared__ __align__(16) ushort xplane[2048];        // 4KB (x halo, 8ch/pos)
    __shared__ __align__(16) uint4  bslab[3 * 256];      // 12KB B slab ring

    const int tid = threadIdx.x;
    const int x0 = blockIdx.x * 16, y0 = blockIdx.y * 12;
    const int bb = blockIdx.z >> 2, slice = blockIdx.z & 3;

    const uint4* gB = (const uint4*)Bp + (size_t)(slice * 21) * 256 + tid;
    async16(gB,       &bslab[tid]);            // slab 0
    async16(gB + 256, &bslab[256 + tid]);      // slab 1

    // stage 14x18 halo (pos = tid, 0..251 valid; 252..255 loaded but never read)
    {
        int py = tid / 18, px = tid - py * 18;
        int gy = y0 - 1 + py, gx = x0 - 1 + px;
        bool ok = (gy >= 0 && gy < HTOT && gx >= 0 && gx < WTOT);
        int gyc = gy < 0 ? 0 : (gy > HTOT - 1 ? HTOT - 1 : gy);
        int gxc = gx < 0 ? 0 : (gx > WTOT - 1 ? WTOT - 1 : gx);
        size_t gpos = ((size_t)bb * HTOT + gyc) * WTOT + gxc;
        #pragma unroll
        for (int p = 0; p < 8; ++p) {
            const void* src = ok
                ? (const void*)(hS_in + ((size_t)(p >> 1) * NPOS + gpos) * 16 + (p & 1) * 8)
                : (const void*)zpad;
            async16(src, hplanes + p * 2048 + tid * 8);
        }
        const void* sxp = ok
            ? (const void*)(xbf + ((((size_t)bb * TT + t) * HTOT + gyc) * WTOT + gxc) * CINX)
            : (const void*)zpad;
        async16(sxp, xplane + tid * 8);
    }

    const int w = tid >> 6, lane = tid & 63, q = lane >> 4, col = lane & 15;
    const int rowb = w * 3;                    // wave rows rowb..rowb+2 (of 12)

    const ushort* hA = hplanes + q * 2048 + (rowb * 18 + col) * 8;  // per-lane base
    const uint4*  bA = bslab + lane;

    floatx4 acc[3][4];
    #pragma unroll
    for (int g = 0; g < 4; ++g) {
        float bv = bias[g * 64 + slice * 16 + col];
        acc[0][g] = (floatx4){bv, bv, bv, bv};
        acc[1][g] = (floatx4){bv, bv, bv, bv};
        acc[2][g] = (floatx4){bv, bv, bv, bv};
    }

    __syncthreads();   // drains all prologue async loads (vmcnt 0)

    // ---- K-loop: s = dx*6 + kh*3 + dy; slab slot = dy; A-window ring of 4 ----
    U16 aw[4];
    #pragma unroll
    for (int dx = 0; dx < 3; ++dx) {
        #pragma unroll
        for (int kh = 0; kh < 2; ++kh) {
            #pragma unroll
            for (int j = 0; j < 3; ++j)        // prime rows 0..2 -> slots 0..2
                aw[j].u = *(const uint4*)(hA + kh * 8192 + j * 144 + dx * 8);
            #pragma unroll
            for (int dy = 0; dy < 3; ++dy) {
                const int s = dx * 6 + kh * 3 + dy;
                if (dy)                         // slide: row dy+2 -> slot (dy+2)&3
                    aw[(dy + 2) & 3].u = *(const uint4*)(hA + kh * 8192 + (dy + 2) * 144 + dx * 8);
                async16(gB + (s + 2) * 256, &bslab[((dy + 2) % 3) * 256 + tid]);
                #pragma unroll
                for (int g = 0; g < 4; ++g) {
                    U16 b4; b4.u = bA[dy * 256 + g * 64];
                    #pragma unroll
                    for (int mt = 0; mt < 3; ++mt)
                        acc[mt][g] = __builtin_amdgcn_mfma_f32_16x16x32_bf16(
                            aw[(mt + dy) & 3].s, b4.s, acc[mt][g], 0, 0, 0);
                }
                // slab s+1 must be resident for next step; s+2 stays in flight
                asm volatile("s_waitcnt vmcnt(1)" ::: "memory");
                __builtin_amdgcn_s_barrier();
                __builtin_amdgcn_sched_barrier(0);
            }
        }
    }
    // ---- x phase: s = 18,19,20 (slab slots 0,1,2) ----
    #pragma unroll
    for (int sx = 0; sx < 3; ++sx) {
        int tap = sx * 4 + q; if (tap > 8) tap = 8;   // padded taps: B rows are 0
        int dyq = tap / 3, dxq = tap - 3 * dyq;
        const ushort* xA = xplane + ((rowb + dyq) * 18 + col + dxq) * 8;
        if (sx == 0) async16(gB + 20 * 256, &bslab[2 * 256 + tid]);  // slab 20
        U16 a4[3];
        #pragma unroll
        for (int mt = 0; mt < 3; ++mt)
            a4[mt].u = *(const uint4*)(xA + mt * 144);
        #pragma unroll
        for (int g = 0; g < 4; ++g) {
            U16 b4; b4.u = bA[sx * 256 + g * 64];
            #pragma unroll
            for (int mt = 0; mt < 3; ++mt)
                acc[mt][g] = __builtin_amdgcn_mfma_f32_16x16x32_bf16(
                    a4[mt].s, b4.s, acc[mt][g], 0, 0, 0);
        }
        if (sx == 0) {
            asm volatile("s_waitcnt vmcnt(1)" ::: "memory");
            __builtin_amdgcn_s_barrier();
            __builtin_amdgcn_sched_barrier(0);
        } else if (sx == 1) {
            asm volatile("s_waitcnt vmcnt(0)" ::: "memory");
            __builtin_amdgcn_s_barrier();
            __builtin_amdgcn_sched_barrier(0);
        }
    }

    // ---- epilogue: gates fused in-register; contiguous slice-major writes ----
    #pragma unroll
    for (int mt = 0; mt < 3; ++mt) {
        int gy = y0 + rowb + mt;
        #pragma unroll
        for (int r = 0; r < 4; ++r) {
            int gx = x0 + q * 4 + r;
            size_t gpos = ((size_t)bb * HTOT + gy) * WTOT + gx;
            size_t idx = ((size_t)slice * NPOS + gpos) * 16 + col;
            float zi = acc[mt][0][r], zf = acc[mt][1][r];
            float zg = acc[mt][2][r], zo = acc[mt][3][r];
            float cn = hsig(zf) * cS[idx] + hsig(zi) * ftanh(zg);
            cS[idx] = cn;
            float hn = hsig(zo) * ftanh(cn);
            hS_out[idx] = f2bf(hn);
            if (last) out[gpos * 64 + slice * 16 + col] = hn;
        }
    }
}

extern "C" void kernel_launch(void* const* d_in, const int* in_sizes, int n_in,
                              void* d_out, int out_size, void* d_ws, size_t ws_size,
                              hipStream_t stream) {
    const float* x  = (const float*)d_in[0];
    const float* Wx = (const float*)d_in[1];
    const float* Wh = (const float*)d_in[2];
    const float* b  = (const float*)d_in[3];

    const size_t NX = (size_t)BB * TT * HTOT * WTOT * CINX;  // 9,437,184
    const size_t NH = (size_t)NPOS * FF;                     // 4,718,592

    char* ws = (char*)d_ws;
    ushort* xbf = (ushort*)ws;                  ws += NX * 2;            // 18.9 MB
    ushort* hS0 = (ushort*)ws;                  ws += NH * 2;            //  9.4 MB
    ushort* hS1 = (ushort*)ws;                  ws += NH * 2;            //  9.4 MB
    float*  cS  = (float*)ws;                   ws += NH * 4;            // 18.9 MB
    ushort* Bp  = (ushort*)ws;                  ws += (size_t)4*21*256*16; // 344 KB
    uint4*  zpad = (uint4*)ws;                                           // 64 B zeros

    hipMemsetAsync(hS0, 0, NH * 2, stream);
    hipMemsetAsync(cS,  0, NH * 4, stream);
    hipMemsetAsync(zpad, 0, 64, stream);

    conv_x_bf16<<<(int)((NX / 4 + 255) / 256), 256, 0, stream>>>(x, xbf, (int)(NX / 4));
    prep_w<<<(4 * 21 * 256 + 255) / 256, 256, 0, stream>>>(Wx, Wh, Bp);

    dim3 grid(WTOT / 16, HTOT / 12, BB * 4);
    for (int t = 0; t < TT; ++t) {
        const ushort* hin = (t & 1) ? hS1 : hS0;
        ushort* hout      = (t & 1) ? hS0 : hS1;
        convlstm_mfma<<<grid, 256, 0, stream>>>(xbf, t, hin, hout, cS, Bp, b, zpad,
                                                (float*)d_out, t == TT - 1);
    }
}